// Round 11
// baseline (343.472 us; speedup 1.0000x reference)
//
#include <hip/hip_runtime.h>
#include <hip/hip_bf16.h>
#include <stdint.h>

#define DIM   3072
#define BATCH 16384

typedef __attribute__((ext_vector_type(8))) short bf16x8;
typedef __attribute__((ext_vector_type(4))) float f32x4;

__device__ __forceinline__ unsigned short f2b(float f) {
    union { float f; unsigned u; } c; c.f = f;
    unsigned u = c.u;
    unsigned r = (u + 0x7fffu + ((u >> 16) & 1u)) >> 16;
    return (unsigned short)r;
}

// ======== merged pre-pass (R6-proven) ========
#define NWT   2304
#define NCVT  2048
__global__ __launch_bounds__(256) void prep_kernel(const float* __restrict__ w,
                                                   const float* __restrict__ mask,
                                                   const float* __restrict__ x,
                                                   ushort* __restrict__ wt,
                                                   ushort* __restrict__ xb) {
    if (blockIdx.x < NWT) {
        __shared__ float tile[64][65];
        const int u0 = (blockIdx.x % 48) * 64;
        const int d0 = (blockIdx.x / 48) * 64;
        const int t  = threadIdx.x;
        const int rr = t >> 4, cc = t & 15;
#pragma unroll
        for (int it = 0; it < 4; ++it) {
            int drow = it * 16 + rr;
            float4 v = *reinterpret_cast<const float4*>(&w[(size_t)(d0 + drow) * DIM + u0 + cc * 4]);
            tile[drow][cc * 4 + 0] = v.x;
            tile[drow][cc * 4 + 1] = v.y;
            tile[drow][cc * 4 + 2] = v.z;
            tile[drow][cc * 4 + 3] = v.w;
        }
        __syncthreads();
#pragma unroll
        for (int it = 0; it < 4; ++it) {
            int urow = it * 16 + rr;
            float4 mv = *reinterpret_cast<const float4*>(&mask[(size_t)(u0 + urow) * DIM + d0 + cc * 4]);
            ushort4 o;
            o.x = f2b(tile[cc * 4 + 0][urow] * mv.x);
            o.y = f2b(tile[cc * 4 + 1][urow] * mv.y);
            o.z = f2b(tile[cc * 4 + 2][urow] * mv.z);
            o.w = f2b(tile[cc * 4 + 3][urow] * mv.w);
            *reinterpret_cast<ushort4*>(&wt[(size_t)(u0 + urow) * DIM + d0 + cc * 4]) = o;
        }
    } else {
        const int n4 = BATCH * DIM / 4;
        const int stride = NCVT * 256;
        for (int i = (blockIdx.x - NWT) * 256 + threadIdx.x; i < n4; i += stride) {
            float4 v = reinterpret_cast<const float4*>(x)[i];
            ushort4 o;
            o.x = f2b(v.x); o.y = f2b(v.y); o.z = f2b(v.z); o.w = f2b(v.w);
            reinterpret_cast<ushort4*>(xb)[i] = o;
        }
    }
}

#define GLOAD_LDS16(g, l)                                                                 \
    __builtin_amdgcn_global_load_lds((const __attribute__((address_space(1))) void*)(g),  \
                                     (__attribute__((address_space(3))) void*)(l), 16, 0, 0)

// ============== persistent 256² 8-phase bf16 GEMM — single barrier per phase ==============
// R8 skeleton with the ENDPHASE barrier removed. Per phase:
//   { LDA/LDB reads; [vmcnt(2) @P4/P8]; barrier; lgkmcnt(0); sched_barrier;
//     STAGE; setprio(1); MFMA; setprio(0) }
// Safety: STAGE(p) issues only after barrier(p), which all waves reach only after their
// lgkmcnt(0)+MFMA of p-1 -> no stage-write can land under an in-flight prior read.
// Reads of p cannot hoist above p's sched_barrier (after barrier+vmcnt -> staged data
// visible). STAGE cannot cross the memory-clobbered waitcnt asms -> vmcnt counts exact.
__global__ __launch_bounds__(512, 1) void gemm8p(const ushort* __restrict__ A,
                                                 const ushort* __restrict__ B,
                                                 const float* __restrict__ bias,
                                                 float* __restrict__ C) {
    __shared__ ushort sh[2 * 2 * 16384];   // [buf][side A=0/B=1][256][64] : 128 KB

    const int tid  = threadIdx.x;
    const int lane = tid & 63;
    const int wid  = tid >> 6;   // 0..7
    const int wr   = wid >> 2;   // 0..1  (M)
    const int wc   = wid & 3;    // 0..3  (N)
    const int l15  = lane & 15;
    const int kg   = lane >> 4;
    const int sx   = lane & 7;

    const int srow = lane >> 3;
    const int sg   = (lane & 7) ^ srow;

    const int bx  = blockIdx.x;
    const int xcd = bx & 7, loc = bx >> 3;
    int q    = xcd * 96 + loc;
    int brow = (q / 12) * 256, bcol = (q % 12) * 256;
    int nrow = brow, ncol = bcol, nvalid = 0;

    f32x4 acc[8][4] = {};
    bf16x8 a_[8], b0_[4], b1_[4];
    const f32x4 fzero = {};

#define STAGE(b, side, h, tt)                                                              \
    do {                                                                                   \
        int _tt = (tt);                                                                    \
        int _t  = (_tt < 48) ? _tt : (nvalid ? _tt - 48 : 47);                             \
        int _rb = (_tt < 48) ? ((side) ? bcol : brow) : ((side) ? ncol : nrow);            \
        const ushort* _base = (side) ? B : A;                                              \
        int _r0 = _rb + (h) * 128 + wid * 16 + srow;                                       \
        const ushort* _g0 = _base + (size_t)_r0 * DIM + _t * 64 + sg * 8;                  \
        ushort* _l0 = sh + ((b) * 2 + (side)) * 16384 + (h) * 8192 + wid * 1024;           \
        GLOAD_LDS16(_g0, _l0);                                                             \
        GLOAD_LDS16(_g0 + (size_t)8 * DIM, _l0 + 512);                                     \
    } while (0)

#define LDA(QB, QM)                                                                        \
    _Pragma("unroll") for (int fm = 0; fm < 4; ++fm)                                       \
    _Pragma("unroll") for (int ks = 0; ks < 2; ++ks)                                       \
        a_[fm * 2 + ks] = *reinterpret_cast<const bf16x8*>(                                \
            sh + (QB) * 32768 + (wr * 128 + (QM) * 64 + fm * 16 + l15) * 64 +              \
            (((ks * 4 + kg) ^ sx) * 8));

#define LDB(DST, QB, QN)                                                                   \
    _Pragma("unroll") for (int fn = 0; fn < 2; ++fn)                                       \
    _Pragma("unroll") for (int ks = 0; ks < 2; ++ks)                                       \
        DST[fn * 2 + ks] = *reinterpret_cast<const bf16x8*>(                               \
            sh + (QB) * 32768 + 16384 + (wc * 64 + (QN) * 32 + fn * 16 + l15) * 64 +       \
            (((ks * 4 + kg) ^ sx) * 8));

#define MMQ(QM, QN, BARR)                                                                  \
    _Pragma("unroll") for (int fm = 0; fm < 4; ++fm)                                       \
    _Pragma("unroll") for (int fn = 0; fn < 2; ++fn)                                       \
    _Pragma("unroll") for (int ks = 0; ks < 2; ++ks)                                       \
        acc[(QM) * 4 + fm][(QN) * 2 + fn] = __builtin_amdgcn_mfma_f32_16x16x32_bf16(       \
            a_[fm * 2 + ks], BARR[fn * 2 + ks], acc[(QM) * 4 + fm][(QN) * 2 + fn], 0, 0, 0);

    // single barrier per phase: sync, drain this wave's reads, fence
#define SYNC1()                                                                            \
    __builtin_amdgcn_s_barrier();                                                          \
    asm volatile("s_waitcnt lgkmcnt(0)" ::: "memory");                                     \
    __builtin_amdgcn_sched_barrier(0);

#define MM(QM, QN, BARR)                                                                   \
    __builtin_amdgcn_s_setprio(1);                                                         \
    MMQ(QM, QN, BARR);                                                                     \
    __builtin_amdgcn_s_setprio(0);

#define VMW(N) asm volatile("s_waitcnt vmcnt(" #N ")" ::: "memory");

    // ---- prologue (tile 0): t0 fully -> buf0, B(t1) -> buf1; leave t1.B in flight ----
    STAGE(0, 0, 0, 0);
    STAGE(0, 0, 1, 0);
    STAGE(0, 1, 0, 0);
    STAGE(0, 1, 1, 0);
    STAGE(1, 1, 0, 1);
    STAGE(1, 1, 1, 1);
    VMW(4);
    __builtin_amdgcn_s_barrier();

    for (int r = 0; r < 3; ++r) {
        nvalid = (r < 2);
        int qn = nvalid ? (xcd * 96 + (r + 1) * 32 + loc) : q;
        nrow = (qn / 12) * 256;
        ncol = (qn % 12) * 256;

        float bv[4];
#pragma unroll
        for (int n = 0; n < 4; ++n) bv[n] = bias[bcol + wc * 64 + n * 16 + l15];

        for (int t = 0; t < 48; t += 2) {
            // P1: reads t.Q(0,0) | stage A0(t+1)->buf1 | MFMA Q(0,0)
            LDA(0, 0); LDB(b0_, 0, 0);
            SYNC1();
            STAGE(1, 0, 0, t + 1);
            MM(0, 0, b0_);
            // P2: reads b1_ | stage A1(t+1)->buf1 | MFMA Q(0,1)
            LDB(b1_, 0, 1);
            SYNC1();
            STAGE(1, 0, 1, t + 1);
            MM(0, 1, b1_);
            // P3: reads LDA(0,1) | stage B0(t+2)->buf0 | MFMA Q(1,0)
            LDA(0, 1);
            SYNC1();
            STAGE(0, 1, 0, t + 2);
            MM(1, 0, b0_);
            // P4: vmcnt(2) pre-barrier (drain t+1 A+B, leave B0(t+2)) | stage B1(t+2) | Q(1,1)
            VMW(2);
            SYNC1();
            STAGE(0, 1, 1, t + 2);
            MM(1, 1, b1_);
            // P5: reads t+1.Q(0,0) (buf1) | stage A0(t+2)->buf0 | MFMA Q(0,0)
            LDA(1, 0); LDB(b0_, 1, 0);
            SYNC1();
            STAGE(0, 0, 0, t + 2);
            MM(0, 0, b0_);
            // P6: reads b1_ | stage A1(t+2)->buf0 | MFMA Q(0,1)
            LDB(b1_, 1, 1);
            SYNC1();
            STAGE(0, 0, 1, t + 2);
            MM(0, 1, b1_);
            // P7: reads LDA(1,1) | stage B0(t+3)->buf1 | MFMA Q(1,0)
            LDA(1, 1);
            SYNC1();
            STAGE(1, 1, 0, t + 3);
            MM(1, 0, b0_);
            // P8: vmcnt(2) pre-barrier (drain t+2 A+B, leave B0(t+3)) | stage B1(t+3) | Q(1,1)
            VMW(2);
            SYNC1();
            STAGE(1, 1, 1, t + 3);
            MM(1, 1, b1_);
        }

        // ---- epilogue: C/D layout col=lane&15, row=(lane>>4)*4+rr ----
#pragma unroll
        for (int n = 0; n < 4; ++n) {
            int col = bcol + wc * 64 + n * 16 + l15;
#pragma unroll
            for (int m = 0; m < 8; ++m) {
                int row0 = brow + wr * 128 + m * 16 + kg * 4;
#pragma unroll
                for (int rr = 0; rr < 4; ++rr)
                    C[(size_t)(row0 + rr) * DIM + col] = acc[m][n][rr] + bv[n];
            }
        }
        if (r < 2) {
#pragma unroll
            for (int m = 0; m < 8; ++m)
#pragma unroll
                for (int n = 0; n < 4; ++n)
                    acc[m][n] = fzero;
        }
        q = qn; brow = nrow; bcol = ncol;
    }
#undef STAGE
#undef LDA
#undef LDB
#undef MMQ
#undef SYNC1
#undef MM
#undef VMW
}

extern "C" void kernel_launch(void* const* d_in, const int* in_sizes, int n_in,
                              void* d_out, int out_size, void* d_ws, size_t ws_size,
                              hipStream_t stream) {
    const float* x    = (const float*)d_in[0];
    const float* w    = (const float*)d_in[1];
    const float* bias = (const float*)d_in[2];
    const float* mask = (const float*)d_in[3];
    float* out = (float*)d_out;

    const size_t wt_bytes = (size_t)DIM * DIM * sizeof(ushort);
    const size_t xb_off   = (wt_bytes + 255) & ~(size_t)255;

    ushort* wt = (ushort*)d_ws;
    ushort* xb = (ushort*)((char*)d_ws + xb_off);

    prep_kernel<<<NWT + NCVT, 256, 0, stream>>>(w, mask, x, wt, xb);
    gemm8p<<<256, 512, 0, stream>>>(xb, wt, bias, out);
}

// Round 12
// 338.518 us; speedup vs baseline: 1.0146x; 1.0146x over previous
//
#include <hip/hip_runtime.h>
#include <hip/hip_bf16.h>
#include <stdint.h>

#define DIM   3072
#define BATCH 16384

typedef __attribute__((ext_vector_type(8))) short bf16x8;
typedef __attribute__((ext_vector_type(4))) float f32x4;

__device__ __forceinline__ unsigned short f2b(float f) {
    union { float f; unsigned u; } c; c.f = f;
    unsigned u = c.u;
    unsigned r = (u + 0x7fffu + ((u >> 16) & 1u)) >> 16;
    return (unsigned short)r;
}

// ======== merged pre-pass (R6-proven) ========
#define NWT   2304
#define NCVT  2048
__global__ __launch_bounds__(256) void prep_kernel(const float* __restrict__ w,
                                                   const float* __restrict__ mask,
                                                   const float* __restrict__ x,
                                                   ushort* __restrict__ wt,
                                                   ushort* __restrict__ xb) {
    if (blockIdx.x < NWT) {
        __shared__ float tile[64][65];
        const int u0 = (blockIdx.x % 48) * 64;
        const int d0 = (blockIdx.x / 48) * 64;
        const int t  = threadIdx.x;
        const int rr = t >> 4, cc = t & 15;
#pragma unroll
        for (int it = 0; it < 4; ++it) {
            int drow = it * 16 + rr;
            float4 v = *reinterpret_cast<const float4*>(&w[(size_t)(d0 + drow) * DIM + u0 + cc * 4]);
            tile[drow][cc * 4 + 0] = v.x;
            tile[drow][cc * 4 + 1] = v.y;
            tile[drow][cc * 4 + 2] = v.z;
            tile[drow][cc * 4 + 3] = v.w;
        }
        __syncthreads();
#pragma unroll
        for (int it = 0; it < 4; ++it) {
            int urow = it * 16 + rr;
            float4 mv = *reinterpret_cast<const float4*>(&mask[(size_t)(u0 + urow) * DIM + d0 + cc * 4]);
            ushort4 o;
            o.x = f2b(tile[cc * 4 + 0][urow] * mv.x);
            o.y = f2b(tile[cc * 4 + 1][urow] * mv.y);
            o.z = f2b(tile[cc * 4 + 2][urow] * mv.z);
            o.w = f2b(tile[cc * 4 + 3][urow] * mv.w);
            *reinterpret_cast<ushort4*>(&wt[(size_t)(u0 + urow) * DIM + d0 + cc * 4]) = o;
        }
    } else {
        const int n4 = BATCH * DIM / 4;
        const int stride = NCVT * 256;
        for (int i = (blockIdx.x - NWT) * 256 + threadIdx.x; i < n4; i += stride) {
            float4 v = reinterpret_cast<const float4*>(x)[i];
            ushort4 o;
            o.x = f2b(v.x); o.y = f2b(v.y); o.z = f2b(v.z); o.w = f2b(v.w);
            reinterpret_cast<ushort4*>(xb)[i] = o;
        }
    }
}

#define GLOAD_LDS16(g, l)                                                                 \
    __builtin_amdgcn_global_load_lds((const __attribute__((address_space(1))) void*)(g),  \
                                     (__attribute__((address_space(3))) void*)(l), 16, 0, 0)

// ============== persistent 256² 8-phase bf16 GEMM — single barrier, compiler lgkm ==============
// R11 skeleton; the explicit lgkmcnt(0) drain is removed from SYNC1. Plain-C++ ds_reads
// let the compiler emit counted lgkmcnt(N) before each consuming MFMA, so early MFMAs
// start while tail reads are still landing. Cross-wave safety: reads(p) are consumed by
// MFMA(p) (compiler-enforced lgkm waits) and MFMA(p) cannot sink past barrier(p+1)'s
// sched_barrier; STAGE(p+1) is post-barrier(p+1) -> no stage-over-live-read.
__global__ __launch_bounds__(512, 1) void gemm8p(const ushort* __restrict__ A,
                                                 const ushort* __restrict__ B,
                                                 const float* __restrict__ bias,
                                                 float* __restrict__ C) {
    __shared__ ushort sh[2 * 2 * 16384];   // [buf][side A=0/B=1][256][64] : 128 KB

    const int tid  = threadIdx.x;
    const int lane = tid & 63;
    const int wid  = tid >> 6;   // 0..7
    const int wr   = wid >> 2;   // 0..1  (M)
    const int wc   = wid & 3;    // 0..3  (N)
    const int l15  = lane & 15;
    const int kg   = lane >> 4;
    const int sx   = lane & 7;

    const int srow = lane >> 3;
    const int sg   = (lane & 7) ^ srow;

    const int bx  = blockIdx.x;
    const int xcd = bx & 7, loc = bx >> 3;
    int q    = xcd * 96 + loc;
    int brow = (q / 12) * 256, bcol = (q % 12) * 256;
    int nrow = brow, ncol = bcol, nvalid = 0;

    f32x4 acc[8][4] = {};
    bf16x8 a_[8], b0_[4], b1_[4];
    const f32x4 fzero = {};

#define STAGE(b, side, h, tt)                                                              \
    do {                                                                                   \
        int _tt = (tt);                                                                    \
        int _t  = (_tt < 48) ? _tt : (nvalid ? _tt - 48 : 47);                             \
        int _rb = (_tt < 48) ? ((side) ? bcol : brow) : ((side) ? ncol : nrow);            \
        const ushort* _base = (side) ? B : A;                                              \
        int _r0 = _rb + (h) * 128 + wid * 16 + srow;                                       \
        const ushort* _g0 = _base + (size_t)_r0 * DIM + _t * 64 + sg * 8;                  \
        ushort* _l0 = sh + ((b) * 2 + (side)) * 16384 + (h) * 8192 + wid * 1024;           \
        GLOAD_LDS16(_g0, _l0);                                                             \
        GLOAD_LDS16(_g0 + (size_t)8 * DIM, _l0 + 512);                                     \
    } while (0)

#define LDA(QB, QM)                                                                        \
    _Pragma("unroll") for (int fm = 0; fm < 4; ++fm)                                       \
    _Pragma("unroll") for (int ks = 0; ks < 2; ++ks)                                       \
        a_[fm * 2 + ks] = *reinterpret_cast<const bf16x8*>(                                \
            sh + (QB) * 32768 + (wr * 128 + (QM) * 64 + fm * 16 + l15) * 64 +              \
            (((ks * 4 + kg) ^ sx) * 8));

#define LDB(DST, QB, QN)                                                                   \
    _Pragma("unroll") for (int fn = 0; fn < 2; ++fn)                                       \
    _Pragma("unroll") for (int ks = 0; ks < 2; ++ks)                                       \
        DST[fn * 2 + ks] = *reinterpret_cast<const bf16x8*>(                               \
            sh + (QB) * 32768 + 16384 + (wc * 64 + (QN) * 32 + fn * 16 + l15) * 64 +       \
            (((ks * 4 + kg) ^ sx) * 8));

#define MMQ(QM, QN, BARR)                                                                  \
    _Pragma("unroll") for (int fm = 0; fm < 4; ++fm)                                       \
    _Pragma("unroll") for (int fn = 0; fn < 2; ++fn)                                       \
    _Pragma("unroll") for (int ks = 0; ks < 2; ++ks)                                       \
        acc[(QM) * 4 + fm][(QN) * 2 + fn] = __builtin_amdgcn_mfma_f32_16x16x32_bf16(       \
            a_[fm * 2 + ks], BARR[fn * 2 + ks], acc[(QM) * 4 + fm][(QN) * 2 + fn], 0, 0, 0);

    // single barrier per phase; lgkm waits are compiler-inserted (counted) at MFMA use
#define SYNC1()                                                                            \
    __builtin_amdgcn_s_barrier();                                                          \
    __builtin_amdgcn_sched_barrier(0);

#define MM(QM, QN, BARR)                                                                   \
    __builtin_amdgcn_s_setprio(1);                                                         \
    MMQ(QM, QN, BARR);                                                                     \
    __builtin_amdgcn_s_setprio(0);

#define VMW(N) asm volatile("s_waitcnt vmcnt(" #N ")" ::: "memory");

    // ---- prologue (tile 0): t0 fully -> buf0, B(t1) -> buf1; leave t1.B in flight ----
    STAGE(0, 0, 0, 0);
    STAGE(0, 0, 1, 0);
    STAGE(0, 1, 0, 0);
    STAGE(0, 1, 1, 0);
    STAGE(1, 1, 0, 1);
    STAGE(1, 1, 1, 1);
    VMW(4);
    __builtin_amdgcn_s_barrier();

    for (int r = 0; r < 3; ++r) {
        nvalid = (r < 2);
        int qn = nvalid ? (xcd * 96 + (r + 1) * 32 + loc) : q;
        nrow = (qn / 12) * 256;
        ncol = (qn % 12) * 256;

        float bv[4];
#pragma unroll
        for (int n = 0; n < 4; ++n) bv[n] = bias[bcol + wc * 64 + n * 16 + l15];

        for (int t = 0; t < 48; t += 2) {
            // P1: reads t.Q(0,0) | stage A0(t+1)->buf1 | MFMA Q(0,0)
            LDA(0, 0); LDB(b0_, 0, 0);
            SYNC1();
            STAGE(1, 0, 0, t + 1);
            MM(0, 0, b0_);
            // P2: reads b1_ | stage A1(t+1)->buf1 | MFMA Q(0,1)
            LDB(b1_, 0, 1);
            SYNC1();
            STAGE(1, 0, 1, t + 1);
            MM(0, 1, b1_);
            // P3: reads LDA(0,1) | stage B0(t+2)->buf0 | MFMA Q(1,0)
            LDA(0, 1);
            SYNC1();
            STAGE(0, 1, 0, t + 2);
            MM(1, 0, b0_);
            // P4: vmcnt(2) pre-barrier (drain t+1 A+B, leave B0(t+2)) | stage B1(t+2) | Q(1,1)
            VMW(2);
            SYNC1();
            STAGE(0, 1, 1, t + 2);
            MM(1, 1, b1_);
            // P5: reads t+1.Q(0,0) (buf1) | stage A0(t+2)->buf0 | MFMA Q(0,0)
            LDA(1, 0); LDB(b0_, 1, 0);
            SYNC1();
            STAGE(0, 0, 0, t + 2);
            MM(0, 0, b0_);
            // P6: reads b1_ | stage A1(t+2)->buf0 | MFMA Q(0,1)
            LDB(b1_, 1, 1);
            SYNC1();
            STAGE(0, 0, 1, t + 2);
            MM(0, 1, b1_);
            // P7: reads LDA(1,1) | stage B0(t+3)->buf1 | MFMA Q(1,0)
            LDA(1, 1);
            SYNC1();
            STAGE(1, 1, 0, t + 3);
            MM(1, 0, b0_);
            // P8: vmcnt(2) pre-barrier (drain t+2 A+B, leave B0(t+3)) | stage B1(t+3) | Q(1,1)
            VMW(2);
            SYNC1();
            STAGE(1, 1, 1, t + 3);
            MM(1, 1, b1_);
        }

        // ---- epilogue: C/D layout col=lane&15, row=(lane>>4)*4+rr ----
#pragma unroll
        for (int n = 0; n < 4; ++n) {
            int col = bcol + wc * 64 + n * 16 + l15;
#pragma unroll
            for (int m = 0; m < 8; ++m) {
                int row0 = brow + wr * 128 + m * 16 + kg * 4;
#pragma unroll
                for (int rr = 0; rr < 4; ++rr)
                    C[(size_t)(row0 + rr) * DIM + col] = acc[m][n][rr] + bv[n];
            }
        }
        if (r < 2) {
#pragma unroll
            for (int m = 0; m < 8; ++m)
#pragma unroll
                for (int n = 0; n < 4; ++n)
                    acc[m][n] = fzero;
        }
        q = qn; brow = nrow; bcol = ncol;
    }
#undef STAGE
#undef LDA
#undef LDB
#undef MMQ
#undef SYNC1
#undef MM
#undef VMW
}

extern "C" void kernel_launch(void* const* d_in, const int* in_sizes, int n_in,
                              void* d_out, int out_size, void* d_ws, size_t ws_size,
                              hipStream_t stream) {
    const float* x    = (const float*)d_in[0];
    const float* w    = (const float*)d_in[1];
    const float* bias = (const float*)d_in[2];
    const float* mask = (const float*)d_in[3];
    float* out = (float*)d_out;

    const size_t wt_bytes = (size_t)DIM * DIM * sizeof(ushort);
    const size_t xb_off   = (wt_bytes + 255) & ~(size_t)255;

    ushort* wt = (ushort*)d_ws;
    ushort* xb = (ushort*)((char*)d_ws + xb_off);

    prep_kernel<<<NWT + NCVT, 256, 0, stream>>>(w, mask, x, wt, xb);
    gemm8p<<<256, 512, 0, stream>>>(xb, wt, bias, out);
}